// Round 5
// baseline (60136.023 us; speedup 1.0000x reference)
//
#include <hip/hip_runtime.h>

#define Bn 128
#define Tn 1024
#define INn 256
#define Hn 512
#define NB 256   // persistent blocks (1 per CU), 512 threads each

typedef short bf16x8 __attribute__((ext_vector_type(8)));
typedef float f32x4 __attribute__((ext_vector_type(4)));
typedef float f32x4v __attribute__((ext_vector_type(4)));

// ---- ws layout (bytes) ----
#define WHI_OFF  0u
#define WLO_OFF  11534336u
#define BIAS_OFF 23068672u
#define HH_OFF   23093248u
#define HM_OFF   23879680u
#define HL_OFF   24666112u
#define H3F_OFF  25452544u
#define CNT_OFF  25714688u   // 8KB barrier area

__device__ __forceinline__ float sigm(float x) { return 1.0f / (1.0f + __expf(-x)); }
__device__ __forceinline__ unsigned short bf_hi(float x) {
  unsigned u = __builtin_bit_cast(unsigned, x);
  return (unsigned short)(u >> 16);
}
__device__ __forceinline__ float bf_f(unsigned short h) {
  unsigned u = ((unsigned)h) << 16;
  return __builtin_bit_cast(float, u);
}

// Pack fp32 weights into MFMA-fragment-ordered bf16 hi/lo arrays.
// dst elem offset = layer_base + (((jt*2+ns)*NCH + kc)*64 + lane)*8
// col n = ns*16+(lane&15) -> gate row r = (n>>3)*512 + jt*8 + (n&7),
// k0 = kc*32 + (lane>>4)*8 over concat [x ; h]  (same (lane,e)->k map as A-frags).
__global__ void pack_weights(const float* __restrict__ wih1, const float* __restrict__ whh1,
                             const float* __restrict__ wih2, const float* __restrict__ whh2,
                             const float* __restrict__ wih3, const float* __restrict__ whh3,
                             unsigned short* __restrict__ whi, unsigned short* __restrict__ wlo) {
  int gid = blockIdx.x * 256 + threadIdx.x;
  int rem, NCH, kih; size_t base; const float *wih, *whh;
  if (gid < 196608)      { rem = gid;          base = 0;       NCH = 24; kih = 256; wih = wih1; whh = whh1; }
  else if (gid < 458752) { rem = gid - 196608; base = 1572864; NCH = 32; kih = 512; wih = wih2; whh = whh2; }
  else if (gid < 720896) { rem = gid - 458752; base = 3670016; NCH = 32; kih = 512; wih = wih3; whh = whh3; }
  else return;
  const int lane = rem & 63; rem >>= 6;
  const int kc = rem % NCH; rem /= NCH;
  const int ns = rem & 1;
  const int jt = rem >> 1;
  const int n = ns * 16 + (lane & 15);
  const int g = n >> 3, jl = n & 7;
  const int r = g * 512 + jt * 8 + jl;
  const int k0 = kc * 32 + (lane >> 4) * 8;
  const float* src = (k0 < kih) ? (wih + (size_t)r * kih + k0)
                                : (whh + (size_t)r * 512 + (k0 - kih));
  size_t dst = base + ((((size_t)jt * 2 + ns) * NCH + kc) * 64 + lane) * 8;
#pragma unroll
  for (int e = 0; e < 8; ++e) {
    float w = src[e];
    unsigned short h = bf_hi(w);
    whi[dst + e] = h;
    wlo[dst + e] = bf_hi(w - bf_f(h));
  }
}

__global__ void pack_bias(const float* __restrict__ bi1, const float* __restrict__ bh1,
                          const float* __restrict__ bi2, const float* __restrict__ bh2,
                          const float* __restrict__ bi3, const float* __restrict__ bh3,
                          float* __restrict__ bias) {
  int gid = blockIdx.x * 256 + threadIdx.x;
  if (gid >= 6144) return;
  int l = gid >> 11, r = gid & 2047;
  const float* bi = (l == 0) ? bi1 : (l == 1) ? bi2 : bi3;
  const float* bh = (l == 0) ? bh1 : (l == 1) ? bh2 : bh3;
  bias[gid] = bi[r] + bh[r];
}

// ---- fan-out grid barrier ----
// word layout in bar[]: arrival sub-counters (xcd*4+s)*32 (32 lines, 8 RMWs each);
// done flags words 1024+x (one line, 8 writers / 1 poller); epoch word 1056;
// per-XCD broadcast flags 1088+x*32 (1 writer / <=31 pollers each).
__device__ __forceinline__ void gridbar(unsigned* bar, unsigned n, int xcd, int idx) {
  __syncthreads();
  if (threadIdx.x == 0) {
    __threadfence();
    __hip_atomic_fetch_add(bar + (xcd * 4 + (idx & 3)) * 32, 1u,
                           __ATOMIC_RELAXED, __HIP_MEMORY_SCOPE_AGENT);
    if (idx == 0) {
      // XCD representative: wait for all 4 sub-counters to reach 8n
      for (;;) {
        unsigned s0 = __hip_atomic_load(bar + (xcd*4+0)*32, __ATOMIC_RELAXED, __HIP_MEMORY_SCOPE_AGENT);
        unsigned s1 = __hip_atomic_load(bar + (xcd*4+1)*32, __ATOMIC_RELAXED, __HIP_MEMORY_SCOPE_AGENT);
        unsigned s2 = __hip_atomic_load(bar + (xcd*4+2)*32, __ATOMIC_RELAXED, __HIP_MEMORY_SCOPE_AGENT);
        unsigned s3 = __hip_atomic_load(bar + (xcd*4+3)*32, __ATOMIC_RELAXED, __HIP_MEMORY_SCOPE_AGENT);
        if (s0 >= 8*n && s1 >= 8*n && s2 >= 8*n && s3 >= 8*n) break;
        __builtin_amdgcn_s_sleep(1);
      }
      __hip_atomic_store(bar + 1024 + xcd, n, __ATOMIC_RELEASE, __HIP_MEMORY_SCOPE_AGENT);
      if (xcd == 0) {
        for (;;) {
          bool ok = true;
#pragma unroll
          for (int x = 0; x < 8; ++x)
            ok &= (__hip_atomic_load(bar + 1024 + x, __ATOMIC_RELAXED, __HIP_MEMORY_SCOPE_AGENT) >= n);
          if (ok) break;
          __builtin_amdgcn_s_sleep(2);
        }
        __hip_atomic_store(bar + 1056, n, __ATOMIC_RELEASE, __HIP_MEMORY_SCOPE_AGENT);
      }
      while (__hip_atomic_load(bar + 1056, __ATOMIC_RELAXED, __HIP_MEMORY_SCOPE_AGENT) < n)
        __builtin_amdgcn_s_sleep(2);
      __hip_atomic_store(bar + 1088 + xcd * 32, n, __ATOMIC_RELEASE, __HIP_MEMORY_SCOPE_AGENT);
    } else {
      while (__hip_atomic_load(bar + 1088 + xcd * 32, __ATOMIC_RELAXED, __HIP_MEMORY_SCOPE_AGENT) < n)
        __builtin_amdgcn_s_sleep(2);
    }
    (void)__hip_atomic_load(bar + 1056, __ATOMIC_ACQUIRE, __HIP_MEMORY_SCOPE_AGENT);
  }
  __syncthreads();
}

// Persistent fused LSTM: 256 blocks x 512 threads (8 waves/CU, 2/SIMD).
// Block = (b-tile 32, j-tile 8), all 3 layers each phase (layer l at t=p-l).
// Wave w: bsub=w&1 (16 b-rows), nsub=(w>>1)&1 (16 gate-cols), kq=w>>2 (K half).
// A = 3-split bf16 (hi/mid/lo), B = 2-split; 5 MFMAs -> ~2^-24 product error.
// l1-hi kq0-half weights cached in LDS; nt-stores for h; nt-loads for embed.
__global__ __launch_bounds__(512, 2) void lstm_fused(
    const float* __restrict__ embed,
    const unsigned short* __restrict__ whi,
    const unsigned short* __restrict__ wlo,
    const float* __restrict__ bias,
    unsigned short* __restrict__ hh,
    unsigned short* __restrict__ hm,
    unsigned short* __restrict__ hl,
    float* __restrict__ h3f,
    const float* __restrict__ fcw, const float* __restrict__ fcb,
    float* __restrict__ out, unsigned* __restrict__ bar)
{
  const int bid = blockIdx.x;
  const int xcd = bid & 7;
  const int idx = bid >> 3;           // 0..31 within XCD
  const int jt  = xcd * 8 + (idx & 7);
  const int bt  = idx >> 3;           // 0..3
  const int j0  = jt * 8;
  const int b0  = bt * 32;
  const int tid = (int)threadIdx.x;
  const int lane = tid & 63;
  const int w = tid >> 6;
  const int bsub = w & 1, nsub = (w >> 1) & 1, kq = w >> 2;

  __shared__ short wc[2][16][512];      // l1-hi weights, kq0 half (32KB)
  __shared__ float pre[2][2][32][36];   // [parity][kq][brow][gatecol]
  __shared__ float sbias[3][32];

  if (tid < 96) {
    int l = tid >> 5, n = tid & 31;
    sbias[l][n] = bias[l * 2048 + (n >> 3) * 512 + j0 + (n & 7)];
  }
  // fill l1-hi LDS cache (pack_weights ran before this kernel on the stream)
  for (int i = tid * 8; i < 16384; i += 512 * 8) {
    const int ns = i >> 13, rem = i & 8191, kc = rem >> 9, off = rem & 511;
    const size_t g = 1572864u + ((size_t)((jt * 2 + ns) * 32 + kc)) * 512 + off;
    *reinterpret_cast<bf16x8*>(&wc[ns][kc][off]) =
        *reinterpret_cast<const bf16x8*>(whi + g);
  }
  // zero h state (ws poisoned; deterministic per launch)
  for (int i = bid * 512 + tid; i < 3 * 2 * Bn * Hn; i += NB * 512) {
    hh[i] = 0; hm[i] = 0; hl[i] = 0;
  }

  float c0 = 0.f, c1 = 0.f, c2 = 0.f;   // cell state (b0+(tid>>3)&31, j0+(tid&7)), tid<256
  unsigned bidx = 1;
  gridbar(bar, bidx++, xcd, idx);

  const int arow = b0 + bsub * 16 + (lane & 15);   // A-frag b row
  const int kgrp = (lane >> 4) * 8;                // k-offset in 32-chunk
  const int bloc = (tid >> 3) & 31, jl = tid & 7;  // cell-update mapping (tid<256)

  for (int p = 0; p <= 1024; ++p) {
    const int rp = (p + 1) & 1, wp = p & 1;

#pragma unroll
    for (int l = 0; l < 3; ++l) {
      const int t = p - l;
      if (t < 0 || t > 1022) continue;
      const int NCH = (l == 0) ? 24 : 32;
      const int half = NCH >> 1;
      const size_t wbase = (l == 0) ? 0u : ((l == 1) ? 1572864u : 3670016u);
      const unsigned short* wh = whi + wbase + ((size_t)(jt * 2 + nsub) * NCH) * 512 + lane * 8;
      const unsigned short* wl = wlo + wbase + ((size_t)(jt * 2 + nsub) * NCH) * 512 + lane * 8;
      const bool useLDS = (l == 1) && (kq == 0);

      f32x4 accA = {0.f,0.f,0.f,0.f}, accB = {0.f,0.f,0.f,0.f};
      const int kc0 = kq * half;

#pragma unroll
      for (int i = 0; i < 16; ++i) {
        if (i >= half) break;                      // compile-time per l
        const int kc = kc0 + i;
        const int k0 = kc * 32 + kgrp;
        bf16x8 aH, aM, aL;
        if (l == 0 && k0 < 256) {                  // embed fp32 -> 3-split, nt loads
          const float* s = embed + ((size_t)arow * Tn + t) * INn + k0;
          const f32x4v x0 = __builtin_nontemporal_load(reinterpret_cast<const f32x4v*>(s));
          const f32x4v x1 = __builtin_nontemporal_load(reinterpret_cast<const f32x4v*>(s) + 1);
          float xs[8] = {x0.x, x0.y, x0.z, x0.w, x1.x, x1.y, x1.z, x1.w};
#pragma unroll
          for (int e = 0; e < 8; ++e) {
            unsigned short h1 = bf_hi(xs[e]);
            float r1 = xs[e] - bf_f(h1);
            unsigned short m1 = bf_hi(r1);
            aH[e] = (short)h1; aM[e] = (short)m1;
            aL[e] = (short)bf_hi(r1 - bf_f(m1));
          }
        } else {
          int srcl, off;
          if (l == 0)           { srcl = 0;     off = k0 - 256; }
          else if (k0 < 512)    { srcl = l - 1; off = k0;       }
          else                  { srcl = l;     off = k0 - 512; }
          const size_t ho = ((size_t)(srcl * 2 + rp) * Bn + arow) * Hn + off;
          aH = *reinterpret_cast<const bf16x8*>(hh + ho);
          aM = *reinterpret_cast<const bf16x8*>(hm + ho);
          aL = *reinterpret_cast<const bf16x8*>(hl + ho);
        }
        bf16x8 bH;
        if (useLDS) bH = *reinterpret_cast<const bf16x8*>(&wc[nsub][kc][lane * 8]);
        else        bH = *reinterpret_cast<const bf16x8*>(wh + (size_t)kc * 512);
        const bf16x8 bL = *reinterpret_cast<const bf16x8*>(wl + (size_t)kc * 512);
        accA = __builtin_amdgcn_mfma_f32_16x16x32_bf16(aH, bH, accA, 0, 0, 0);
        accA = __builtin_amdgcn_mfma_f32_16x16x32_bf16(aM, bH, accA, 0, 0, 0);
        accA = __builtin_amdgcn_mfma_f32_16x16x32_bf16(aL, bH, accA, 0, 0, 0);
        accB = __builtin_amdgcn_mfma_f32_16x16x32_bf16(aH, bL, accB, 0, 0, 0);
        accB = __builtin_amdgcn_mfma_f32_16x16x32_bf16(aM, bL, accB, 0, 0, 0);
      }

      const int pb = l & 1;  // l0/l2 share plane 0: l0-reads fenced from l2-writes by l1's sync
      {
        const int prow = bsub * 16 + ((lane >> 4) << 2);
        const int pc = nsub * 16 + (lane & 15);
#pragma unroll
        for (int r = 0; r < 4; ++r)
          pre[pb][kq][prow + r][pc] = accA[r] + accB[r];
      }
      __syncthreads();
      if (tid < 256) {
        const float g0 = pre[pb][0][bloc][jl]      + pre[pb][1][bloc][jl]      + sbias[l][jl];
        const float g1 = pre[pb][0][bloc][8 + jl]  + pre[pb][1][bloc][8 + jl]  + sbias[l][8 + jl];
        const float g2 = pre[pb][0][bloc][16 + jl] + pre[pb][1][bloc][16 + jl] + sbias[l][16 + jl];
        const float g3 = pre[pb][0][bloc][24 + jl] + pre[pb][1][bloc][24 + jl] + sbias[l][24 + jl];
        const float ig = sigm(g0), fg = sigm(g1), gg = tanhf(g2), og = sigm(g3);
        float& c = (l == 0) ? c0 : ((l == 1) ? c1 : c2);
        c = fg * c + ig * gg;
        const float hv = og * tanhf(c);
        const unsigned short h1 = bf_hi(hv);
        const float r1 = hv - bf_f(h1);
        const unsigned short m1 = bf_hi(r1);
        const size_t ho = ((size_t)(l * 2 + wp) * Bn + (b0 + bloc)) * Hn + (j0 + jl);
        __builtin_nontemporal_store(h1, hh + ho);
        __builtin_nontemporal_store(m1, hm + ho);
        __builtin_nontemporal_store(bf_hi(r1 - bf_f(m1)), hl + ho);
        if (l == 2 && t == 1022)
          __builtin_nontemporal_store(hv, h3f + (size_t)(b0 + bloc) * Hn + (j0 + jl));
      }
    }
    gridbar(bar, bidx++, xcd, idx);
  }

  // FC epilogue: out2[b][o] = h3_final[b,:] . fc_w[o,:] + fc_b[o]
  const int gid = bid * 512 + tid;
  if (gid < Bn * INn) {
    const int b = gid >> 8, o = gid & 255;
    const float* hr = h3f + (size_t)b * Hn;
    const float* wr = fcw + (size_t)o * Hn;
    float acc = fcb[o];
#pragma unroll 4
    for (int k = 0; k < Hn; k += 4) {
      const float4 hv = *reinterpret_cast<const float4*>(hr + k);
      const float4 wv = *reinterpret_cast<const float4*>(wr + k);
      acc = fmaf(hv.x, wv.x, acc); acc = fmaf(hv.y, wv.y, acc);
      acc = fmaf(hv.z, wv.z, acc); acc = fmaf(hv.w, wv.w, acc);
    }
    out[(size_t)Bn * Tn * INn + gid] = acc;
  }
}

extern "C" void kernel_launch(void* const* d_in, const int* in_sizes, int n_in,
                              void* d_out, int out_size, void* d_ws, size_t ws_size,
                              hipStream_t stream) {
  const float* embed = (const float*)d_in[0];
  const float* wih1  = (const float*)d_in[1];
  const float* whh1  = (const float*)d_in[2];
  const float* bih1  = (const float*)d_in[3];
  const float* bhh1  = (const float*)d_in[4];
  const float* wih2  = (const float*)d_in[5];
  const float* whh2  = (const float*)d_in[6];
  const float* bih2  = (const float*)d_in[7];
  const float* bhh2  = (const float*)d_in[8];
  const float* wih3  = (const float*)d_in[9];
  const float* whh3  = (const float*)d_in[10];
  const float* bih3  = (const float*)d_in[11];
  const float* bhh3  = (const float*)d_in[12];
  const float* fcw   = (const float*)d_in[13];
  const float* fcb   = (const float*)d_in[14];
  float* outp = (float*)d_out;

  char* ws = (char*)d_ws;
  unsigned short* whi = (unsigned short*)(ws + WHI_OFF);
  unsigned short* wlo = (unsigned short*)(ws + WLO_OFF);
  float* bias         = (float*)(ws + BIAS_OFF);
  unsigned short* hh  = (unsigned short*)(ws + HH_OFF);
  unsigned short* hm  = (unsigned short*)(ws + HM_OFF);
  unsigned short* hl  = (unsigned short*)(ws + HL_OFF);
  float* h3f          = (float*)(ws + H3F_OFF);
  unsigned* bar       = (unsigned*)(ws + CNT_OFF);

  // Output 0: embed passthrough (128 MB d2d)
  hipMemcpyAsync(d_out, d_in[0], (size_t)Bn * Tn * INn * sizeof(float),
                 hipMemcpyDeviceToDevice, stream);
  // barrier counters must start at 0 every launch
  hipMemsetAsync(bar, 0, 8192, stream);

  pack_weights<<<2816, 256, 0, stream>>>(wih1, whh1, wih2, whh2, wih3, whh3, whi, wlo);
  pack_bias<<<24, 256, 0, stream>>>(bih1, bhh1, bih2, bhh2, bih3, bhh3, bias);

  void* args[] = { (void*)&embed, (void*)&whi, (void*)&wlo, (void*)&bias,
                   (void*)&hh, (void*)&hm, (void*)&hl, (void*)&h3f,
                   (void*)&fcw, (void*)&fcb, (void*)&outp, (void*)&bar };
  dim3 grid(NB), block(512);
  hipLaunchCooperativeKernel((const void*)lstm_fused, grid, block, args, 0, stream);
}

// Round 6
// 42119.843 us; speedup vs baseline: 1.4277x; 1.4277x over previous
//
#include <hip/hip_runtime.h>

#define Bn 128
#define Tn 1024
#define INn 256
#define Hn 512

typedef short bf16x8 __attribute__((ext_vector_type(8)));
typedef float f32x4 __attribute__((ext_vector_type(4)));

// ---- ws layout (bytes) ----
#define WHI_OFF  0u
#define WLO_OFF  11534336u
#define BIAS_OFF 23068672u
#define HH_OFF   23093248u
#define HM_OFF   23879680u
#define HL_OFF   24666112u
#define CST_OFF  25452544u   // f32 [3][128][512] cell state
#define H3F_OFF  26238976u   // f32 [128][512]

__device__ __forceinline__ float sigm(float x) { return 1.0f / (1.0f + __expf(-x)); }
__device__ __forceinline__ unsigned short bf_hi(float x) {
  unsigned u = __builtin_bit_cast(unsigned, x);
  return (unsigned short)(u >> 16);
}
__device__ __forceinline__ float bf_f(unsigned short h) {
  unsigned u = ((unsigned)h) << 16;
  return __builtin_bit_cast(float, u);
}

// Pack fp32 weights into MFMA-fragment-ordered bf16 hi/lo arrays.
// dst elem offset = layer_base + (((jt*2+ns)*NCH + kc)*64 + lane)*8
// col n = ns*16+(lane&15) -> gate row r = (n>>3)*512 + jt*8 + (n&7),
// k0 = kc*32 + (lane>>4)*8 over concat [x ; h]  (same (lane,e)->k map as A-frags).
__global__ void pack_weights(const float* __restrict__ wih1, const float* __restrict__ whh1,
                             const float* __restrict__ wih2, const float* __restrict__ whh2,
                             const float* __restrict__ wih3, const float* __restrict__ whh3,
                             unsigned short* __restrict__ whi, unsigned short* __restrict__ wlo) {
  int gid = blockIdx.x * 256 + threadIdx.x;
  int rem, NCH, kih; size_t base; const float *wih, *whh;
  if (gid < 196608)      { rem = gid;          base = 0;       NCH = 24; kih = 256; wih = wih1; whh = whh1; }
  else if (gid < 458752) { rem = gid - 196608; base = 1572864; NCH = 32; kih = 512; wih = wih2; whh = whh2; }
  else if (gid < 720896) { rem = gid - 458752; base = 3670016; NCH = 32; kih = 512; wih = wih3; whh = whh3; }
  else return;
  const int lane = rem & 63; rem >>= 6;
  const int kc = rem % NCH; rem /= NCH;
  const int ns = rem & 1;
  const int jt = rem >> 1;
  const int n = ns * 16 + (lane & 15);
  const int g = n >> 3, jl = n & 7;
  const int r = g * 512 + jt * 8 + jl;
  const int k0 = kc * 32 + (lane >> 4) * 8;
  const float* src = (k0 < kih) ? (wih + (size_t)r * kih + k0)
                                : (whh + (size_t)r * 512 + (k0 - kih));
  size_t dst = base + ((((size_t)jt * 2 + ns) * NCH + kc) * 64 + lane) * 8;
#pragma unroll
  for (int e = 0; e < 8; ++e) {
    float w = src[e];
    unsigned short h = bf_hi(w);
    whi[dst + e] = h;
    wlo[dst + e] = bf_hi(w - bf_f(h));
  }
}

__global__ void pack_bias(const float* __restrict__ bi1, const float* __restrict__ bh1,
                          const float* __restrict__ bi2, const float* __restrict__ bh2,
                          const float* __restrict__ bi3, const float* __restrict__ bh3,
                          float* __restrict__ bias) {
  int gid = blockIdx.x * 256 + threadIdx.x;
  if (gid >= 6144) return;
  int l = gid >> 11, r = gid & 2047;
  const float* bi = (l == 0) ? bi1 : (l == 1) ? bi2 : bi3;
  const float* bh = (l == 0) ? bh1 : (l == 1) ? bh2 : bh3;
  bias[gid] = bi[r] + bh[r];
}

__global__ void init_state(unsigned short* __restrict__ hh, unsigned short* __restrict__ hm,
                           unsigned short* __restrict__ hl, float* __restrict__ cst) {
  const int gid = blockIdx.x * 512 + threadIdx.x;   // 512 blocks x 512
  for (int i = gid; i < 3 * 2 * Bn * Hn; i += 512 * 512) { hh[i] = 0; hm[i] = 0; hl[i] = 0; }
  for (int i = gid; i < 3 * Bn * Hn; i += 512 * 512) cst[i] = 0.0f;
}

// One pipeline phase p: layer l processes t = p - l (if in range).
// 256 blocks x 512 threads. Block = (b-tile 32, j-tile 8).
// Wave w: bsub=w&1 (16 b-rows), nsub=(w>>1)&1 (16 gate-cols), kq=w>>2 (K half).
// A = 3-split bf16 (hi/mid/lo), B = 2-split; 5 MFMAs -> ~2^-24 product error.
// Grid barrier = dispatch boundary (stream order); no atomics anywhere.
__global__ __launch_bounds__(512) void lstm_phase(
    int p,
    const float* __restrict__ embed,
    const unsigned short* __restrict__ whi,
    const unsigned short* __restrict__ wlo,
    const float* __restrict__ bias,
    unsigned short* __restrict__ hh,
    unsigned short* __restrict__ hm,
    unsigned short* __restrict__ hl,
    float* __restrict__ cst,
    float* __restrict__ h3f)
{
  const int bid = blockIdx.x;
  const int xcd = bid & 7;
  const int idx = bid >> 3;           // 0..31 within XCD
  const int jt  = xcd * 8 + (idx & 7);
  const int bt  = idx >> 3;           // 0..3
  const int j0  = jt * 8;
  const int b0  = bt * 32;
  const int tid = (int)threadIdx.x;
  const int lane = tid & 63;
  const int w = tid >> 6;
  const int bsub = w & 1, nsub = (w >> 1) & 1, kq = w >> 2;

  __shared__ float pre[2][2][32][36];   // [parity][kq][brow][gatecol]
  __shared__ float sbias[3][32];

  if (tid < 96) {
    int l = tid >> 5, n = tid & 31;
    sbias[l][n] = bias[l * 2048 + (n >> 3) * 512 + j0 + (n & 7)];
  }
  __syncthreads();

  const int rp = (p + 1) & 1, wp = p & 1;
  const int arow = b0 + bsub * 16 + (lane & 15);   // A-frag b row
  const int kgrp = (lane >> 4) * 8;                // k-offset in 32-chunk
  const int bloc = (tid >> 3) & 31, jl = tid & 7;  // cell-update mapping (tid<256)

#pragma unroll
  for (int l = 0; l < 3; ++l) {
    const int t = p - l;
    if (t >= 0 && t <= 1022) {
      const int NCH = (l == 0) ? 24 : 32;
      const int half = NCH >> 1;
      const size_t wbase = (l == 0) ? 0u : ((l == 1) ? 1572864u : 3670016u);
      const unsigned short* wh = whi + wbase + ((size_t)(jt * 2 + nsub) * NCH) * 512 + lane * 8;
      const unsigned short* wl = wlo + wbase + ((size_t)(jt * 2 + nsub) * NCH) * 512 + lane * 8;

      f32x4 accA = {0.f,0.f,0.f,0.f}, accB = {0.f,0.f,0.f,0.f};
      const int kc0 = kq * half;

#pragma unroll
      for (int i = 0; i < 16; ++i) {
        if (i >= half) break;                      // compile-time per l
        const int kc = kc0 + i;
        const int k0 = kc * 32 + kgrp;
        bf16x8 aH, aM, aL;
        if (l == 0 && k0 < 256) {                  // embed fp32 -> 3-split in-register
          const float* s = embed + ((size_t)arow * Tn + t) * INn + k0;
          const f32x4 x0 = __builtin_nontemporal_load(reinterpret_cast<const f32x4*>(s));
          const f32x4 x1 = __builtin_nontemporal_load(reinterpret_cast<const f32x4*>(s) + 1);
          float xs[8] = {x0.x, x0.y, x0.z, x0.w, x1.x, x1.y, x1.z, x1.w};
#pragma unroll
          for (int e = 0; e < 8; ++e) {
            unsigned short h1 = bf_hi(xs[e]);
            float r1 = xs[e] - bf_f(h1);
            unsigned short m1 = bf_hi(r1);
            aH[e] = (short)h1; aM[e] = (short)m1;
            aL[e] = (short)bf_hi(r1 - bf_f(m1));
          }
        } else {
          int srcl, off;
          if (l == 0)           { srcl = 0;     off = k0 - 256; }
          else if (k0 < 512)    { srcl = l - 1; off = k0;       }
          else                  { srcl = l;     off = k0 - 512; }
          const size_t ho = ((size_t)(srcl * 2 + rp) * Bn + arow) * Hn + off;
          aH = *reinterpret_cast<const bf16x8*>(hh + ho);
          aM = *reinterpret_cast<const bf16x8*>(hm + ho);
          aL = *reinterpret_cast<const bf16x8*>(hl + ho);
        }
        const bf16x8 bH = *reinterpret_cast<const bf16x8*>(wh + (size_t)kc * 512);
        const bf16x8 bL = *reinterpret_cast<const bf16x8*>(wl + (size_t)kc * 512);
        accA = __builtin_amdgcn_mfma_f32_16x16x32_bf16(aH, bH, accA, 0, 0, 0);
        accA = __builtin_amdgcn_mfma_f32_16x16x32_bf16(aM, bH, accA, 0, 0, 0);
        accA = __builtin_amdgcn_mfma_f32_16x16x32_bf16(aL, bH, accA, 0, 0, 0);
        accB = __builtin_amdgcn_mfma_f32_16x16x32_bf16(aH, bL, accB, 0, 0, 0);
        accB = __builtin_amdgcn_mfma_f32_16x16x32_bf16(aM, bL, accB, 0, 0, 0);
      }

      const int pb = l & 1;  // l0/l2 share plane 0: separated by l1's __syncthreads
      {
        const int prow = bsub * 16 + ((lane >> 4) << 2);
        const int pc = nsub * 16 + (lane & 15);
#pragma unroll
        for (int r = 0; r < 4; ++r)
          pre[pb][kq][prow + r][pc] = accA[r] + accB[r];
      }
      __syncthreads();
      if (tid < 256) {
        const float g0 = pre[pb][0][bloc][jl]      + pre[pb][1][bloc][jl]      + sbias[l][jl];
        const float g1 = pre[pb][0][bloc][8 + jl]  + pre[pb][1][bloc][8 + jl]  + sbias[l][8 + jl];
        const float g2 = pre[pb][0][bloc][16 + jl] + pre[pb][1][bloc][16 + jl] + sbias[l][16 + jl];
        const float g3 = pre[pb][0][bloc][24 + jl] + pre[pb][1][bloc][24 + jl] + sbias[l][24 + jl];
        const float ig = sigm(g0), fg = sigm(g1), gg = tanhf(g2), og = sigm(g3);
        const size_t ci = (size_t)l * Bn * Hn + (size_t)(b0 + bloc) * Hn + (j0 + jl);
        float c = cst[ci];
        c = fg * c + ig * gg;
        cst[ci] = c;
        const float hv = og * tanhf(c);
        const unsigned short h1 = bf_hi(hv);
        const float r1 = hv - bf_f(h1);
        const unsigned short m1 = bf_hi(r1);
        const size_t ho = ((size_t)(l * 2 + wp) * Bn + (b0 + bloc)) * Hn + (j0 + jl);
        hh[ho] = h1;
        hm[ho] = m1;
        hl[ho] = bf_hi(r1 - bf_f(m1));
        if (l == 2 && t == 1022)
          h3f[(size_t)(b0 + bloc) * Hn + (j0 + jl)] = hv;
      }
    }
  }
}

// FC epilogue: out2[b][o] = h3_final[b,:] . fc_w[o,:] + fc_b[o]
__global__ void fc_kernel(const float* __restrict__ h3f, const float* __restrict__ fcw,
                          const float* __restrict__ fcb, float* __restrict__ out) {
  const int gid = blockIdx.x * 256 + (int)threadIdx.x;
  if (gid >= Bn * INn) return;
  const int b = gid >> 8, o = gid & 255;
  const float* hr = h3f + (size_t)b * Hn;
  const float* wr = fcw + (size_t)o * Hn;
  float acc = fcb[o];
#pragma unroll 4
  for (int k = 0; k < Hn; k += 4) {
    const float4 hv = *reinterpret_cast<const float4*>(hr + k);
    const float4 wv = *reinterpret_cast<const float4*>(wr + k);
    acc = fmaf(hv.x, wv.x, acc); acc = fmaf(hv.y, wv.y, acc);
    acc = fmaf(hv.z, wv.z, acc); acc = fmaf(hv.w, wv.w, acc);
  }
  out[(size_t)Bn * Tn * INn + gid] = acc;
}

extern "C" void kernel_launch(void* const* d_in, const int* in_sizes, int n_in,
                              void* d_out, int out_size, void* d_ws, size_t ws_size,
                              hipStream_t stream) {
  const float* embed = (const float*)d_in[0];
  const float* wih1  = (const float*)d_in[1];
  const float* whh1  = (const float*)d_in[2];
  const float* bih1  = (const float*)d_in[3];
  const float* bhh1  = (const float*)d_in[4];
  const float* wih2  = (const float*)d_in[5];
  const float* whh2  = (const float*)d_in[6];
  const float* bih2  = (const float*)d_in[7];
  const float* bhh2  = (const float*)d_in[8];
  const float* wih3  = (const float*)d_in[9];
  const float* whh3  = (const float*)d_in[10];
  const float* bih3  = (const float*)d_in[11];
  const float* bhh3  = (const float*)d_in[12];
  const float* fcw   = (const float*)d_in[13];
  const float* fcb   = (const float*)d_in[14];
  float* outp = (float*)d_out;

  char* ws = (char*)d_ws;
  unsigned short* whi = (unsigned short*)(ws + WHI_OFF);
  unsigned short* wlo = (unsigned short*)(ws + WLO_OFF);
  float* bias         = (float*)(ws + BIAS_OFF);
  unsigned short* hh  = (unsigned short*)(ws + HH_OFF);
  unsigned short* hm  = (unsigned short*)(ws + HM_OFF);
  unsigned short* hl  = (unsigned short*)(ws + HL_OFF);
  float* cst          = (float*)(ws + CST_OFF);
  float* h3f          = (float*)(ws + H3F_OFF);

  // Output 0: embed passthrough (128 MB d2d)
  hipMemcpyAsync(d_out, d_in[0], (size_t)Bn * Tn * INn * sizeof(float),
                 hipMemcpyDeviceToDevice, stream);

  pack_weights<<<2816, 256, 0, stream>>>(wih1, whh1, wih2, whh2, wih3, whh3, whi, wlo);
  pack_bias<<<24, 256, 0, stream>>>(bih1, bhh1, bih2, bhh2, bih3, bhh3, bias);
  init_state<<<512, 512, 0, stream>>>(hh, hm, hl, cst);

  for (int p = 0; p <= 1024; ++p)
    lstm_phase<<<256, 512, 0, stream>>>(p, embed, whi, wlo, bias, hh, hm, hl, cst, h3f);

  fc_kernel<<<128, 256, 0, stream>>>(h3f, fcw, fcb, outp);
}

// Round 7
// 31241.080 us; speedup vs baseline: 1.9249x; 1.3482x over previous
//
#include <hip/hip_runtime.h>

#define Bn 128
#define Tn 1024
#define INn 256
#define Hn 512

typedef short bf16x8 __attribute__((ext_vector_type(8)));
typedef float f32x4 __attribute__((ext_vector_type(4)));

// ---- ws layout (bytes) ----
#define WHI_OFF  0u
#define WLO_OFF  11534336u
#define BIAS_OFF 23068672u
#define HH_OFF   23093248u   // bf16 [3][2][128][512]
#define HL_OFF   24666112u   // bf16 [3][2][128][512]
#define CST_OFF  26238976u   // f32  [3][128][512]
#define H3F_OFF  27025408u   // f32  [128][512]

__device__ __forceinline__ float sigm(float x) { return 1.0f / (1.0f + __expf(-x)); }
__device__ __forceinline__ unsigned short bf_hi(float x) {
  unsigned u = __builtin_bit_cast(unsigned, x);
  return (unsigned short)(u >> 16);
}
__device__ __forceinline__ float bf_f(unsigned short h) {
  unsigned u = ((unsigned)h) << 16;
  return __builtin_bit_cast(float, u);
}

// Pack fp32 weights into MFMA-fragment-ordered bf16 hi/lo arrays.
// dst elem offset = layer_base + (((jt*2+ns)*NCH + kc)*64 + lane)*8
// col n = ns*16+(lane&15) -> gate row r = (n>>3)*512 + jt*8 + (n&7),
// k0 = kc*32 + (lane>>4)*8 over concat [x ; h]  (same (lane,e)->k map as A-frags).
__global__ void pack_weights(const float* __restrict__ wih1, const float* __restrict__ whh1,
                             const float* __restrict__ wih2, const float* __restrict__ whh2,
                             const float* __restrict__ wih3, const float* __restrict__ whh3,
                             unsigned short* __restrict__ whi, unsigned short* __restrict__ wlo) {
  int gid = blockIdx.x * 256 + threadIdx.x;
  int rem, NCH, kih; size_t base; const float *wih, *whh;
  if (gid < 196608)      { rem = gid;          base = 0;       NCH = 24; kih = 256; wih = wih1; whh = whh1; }
  else if (gid < 458752) { rem = gid - 196608; base = 1572864; NCH = 32; kih = 512; wih = wih2; whh = whh2; }
  else if (gid < 720896) { rem = gid - 458752; base = 3670016; NCH = 32; kih = 512; wih = wih3; whh = whh3; }
  else return;
  const int lane = rem & 63; rem >>= 6;
  const int kc = rem % NCH; rem /= NCH;
  const int ns = rem & 1;
  const int jt = rem >> 1;
  const int n = ns * 16 + (lane & 15);
  const int g = n >> 3, jl = n & 7;
  const int r = g * 512 + jt * 8 + jl;
  const int k0 = kc * 32 + (lane >> 4) * 8;
  const float* src = (k0 < kih) ? (wih + (size_t)r * kih + k0)
                                : (whh + (size_t)r * 512 + (k0 - kih));
  size_t dst = base + ((((size_t)jt * 2 + ns) * NCH + kc) * 64 + lane) * 8;
#pragma unroll
  for (int e = 0; e < 8; ++e) {
    float w = src[e];
    unsigned short h = bf_hi(w);
    whi[dst + e] = h;
    wlo[dst + e] = bf_hi(w - bf_f(h));
  }
}

__global__ void pack_bias(const float* __restrict__ bi1, const float* __restrict__ bh1,
                          const float* __restrict__ bi2, const float* __restrict__ bh2,
                          const float* __restrict__ bi3, const float* __restrict__ bh3,
                          float* __restrict__ bias) {
  int gid = blockIdx.x * 256 + threadIdx.x;
  if (gid >= 6144) return;
  int l = gid >> 11, r = gid & 2047;
  const float* bi = (l == 0) ? bi1 : (l == 1) ? bi2 : bi3;
  const float* bh = (l == 0) ? bh1 : (l == 1) ? bh2 : bh3;
  bias[gid] = bi[r] + bh[r];
}

__global__ void init_state(unsigned short* __restrict__ hh, unsigned short* __restrict__ hl,
                           float* __restrict__ cst) {
  const int gid = blockIdx.x * 512 + threadIdx.x;   // 512 blocks x 512
  for (int i = gid; i < 3 * 2 * Bn * Hn; i += 512 * 512) { hh[i] = 0; hl[i] = 0; }
  for (int i = gid; i < 3 * Bn * Hn; i += 512 * 512) cst[i] = 0.0f;
}

// One pipeline phase p: layer l processes t = p - l (if in range).
// 256 blocks x 1024 threads (16 waves = 4 waves/SIMD for latency hiding).
// Block = (b-tile 32, j-tile 8). Wave w: bsub=w&1 (16 b-rows),
// nsub=(w>>1)&1 (16 gate-cols), kq=w>>2 (K quarter).
// A = 2-split bf16 (hi/lo), B = 2-split; 4 MFMAs (HH+LH+HL+LL).
// Grid barrier = dispatch boundary (hardware-coherent); no atomics.
__global__ __launch_bounds__(1024, 4) void lstm_phase(
    int p,
    const float* __restrict__ embed,
    const unsigned short* __restrict__ whi,
    const unsigned short* __restrict__ wlo,
    const float* __restrict__ bias,
    unsigned short* __restrict__ hh,
    unsigned short* __restrict__ hl,
    float* __restrict__ cst,
    float* __restrict__ h3f)
{
  const int bid = blockIdx.x;
  const int xcd = bid & 7;
  const int idx = bid >> 3;           // 0..31 within XCD
  const int jt  = xcd * 8 + (idx & 7);
  const int bt  = idx >> 3;           // 0..3
  const int j0  = jt * 8;
  const int b0  = bt * 32;
  const int tid = (int)threadIdx.x;
  const int lane = tid & 63;
  const int w = tid >> 6;             // 0..15
  const int bsub = w & 1, nsub = (w >> 1) & 1, kq = w >> 2;   // kq 0..3

  __shared__ float pre[2][4][32][36];   // [parity][kq][brow][gatecol]
  __shared__ float sbias[3][32];

  if (tid < 96) {
    int l = tid >> 5, n = tid & 31;
    sbias[l][n] = bias[l * 2048 + (n >> 3) * 512 + j0 + (n & 7)];
  }
  __syncthreads();

  const int rp = (p + 1) & 1, wp = p & 1;
  const int arow = b0 + bsub * 16 + (lane & 15);   // A-frag b row
  const int kgrp = (lane >> 4) * 8;                // k-offset in 32-chunk
  const int bloc = (tid >> 3) & 31, jl = tid & 7;  // cell-update mapping (tid<256)

#pragma unroll
  for (int l = 0; l < 3; ++l) {
    const int t = p - l;
    if (t >= 0 && t <= 1022) {
      const int NCH = (l == 0) ? 24 : 32;
      const int quarter = NCH >> 2;                // 6 or 8
      const size_t wbase = (l == 0) ? 0u : ((l == 1) ? 1572864u : 3670016u);
      const unsigned short* wh = whi + wbase + ((size_t)(jt * 2 + nsub) * NCH) * 512 + lane * 8;
      const unsigned short* wl = wlo + wbase + ((size_t)(jt * 2 + nsub) * NCH) * 512 + lane * 8;

      f32x4 accA = {0.f,0.f,0.f,0.f}, accB = {0.f,0.f,0.f,0.f};
      const int kc0 = kq * quarter;

#pragma unroll
      for (int i = 0; i < 8; ++i) {
        if (i >= quarter) break;                   // compile-time per l
        const int kc = kc0 + i;
        const int k0 = kc * 32 + kgrp;
        bf16x8 aH, aL;
        if (l == 0 && k0 < 256) {                  // embed fp32 -> 2-split in-register
          const float* s = embed + ((size_t)arow * Tn + t) * INn + k0;
          const f32x4 x0 = __builtin_nontemporal_load(reinterpret_cast<const f32x4*>(s));
          const f32x4 x1 = __builtin_nontemporal_load(reinterpret_cast<const f32x4*>(s) + 1);
          float xs[8] = {x0.x, x0.y, x0.z, x0.w, x1.x, x1.y, x1.z, x1.w};
#pragma unroll
          for (int e = 0; e < 8; ++e) {
            unsigned short h1 = bf_hi(xs[e]);
            aH[e] = (short)h1;
            aL[e] = (short)bf_hi(xs[e] - bf_f(h1));
          }
        } else {
          int srcl, off;
          if (l == 0)           { srcl = 0;     off = k0 - 256; }
          else if (k0 < 512)    { srcl = l - 1; off = k0;       }
          else                  { srcl = l;     off = k0 - 512; }
          const size_t ho = ((size_t)(srcl * 2 + rp) * Bn + arow) * Hn + off;
          aH = *reinterpret_cast<const bf16x8*>(hh + ho);
          aL = *reinterpret_cast<const bf16x8*>(hl + ho);
        }
        const bf16x8 bH = *reinterpret_cast<const bf16x8*>(wh + (size_t)kc * 512);
        const bf16x8 bL = *reinterpret_cast<const bf16x8*>(wl + (size_t)kc * 512);
        accA = __builtin_amdgcn_mfma_f32_16x16x32_bf16(aH, bH, accA, 0, 0, 0);
        accA = __builtin_amdgcn_mfma_f32_16x16x32_bf16(aL, bH, accA, 0, 0, 0);
        accB = __builtin_amdgcn_mfma_f32_16x16x32_bf16(aH, bL, accB, 0, 0, 0);
        accB = __builtin_amdgcn_mfma_f32_16x16x32_bf16(aL, bL, accB, 0, 0, 0);
      }

      const int pb = l & 1;  // l0/l2 share plane 0: separated by l1's __syncthreads
      {
        const int prow = bsub * 16 + ((lane >> 4) << 2);
        const int pc = nsub * 16 + (lane & 15);
#pragma unroll
        for (int r = 0; r < 4; ++r)
          pre[pb][kq][prow + r][pc] = accA[r] + accB[r];
      }
      __syncthreads();
      if (tid < 256) {
        float g0 = sbias[l][jl],      g1 = sbias[l][8 + jl];
        float g2 = sbias[l][16 + jl], g3 = sbias[l][24 + jl];
#pragma unroll
        for (int q = 0; q < 4; ++q) {
          g0 += pre[pb][q][bloc][jl];
          g1 += pre[pb][q][bloc][8 + jl];
          g2 += pre[pb][q][bloc][16 + jl];
          g3 += pre[pb][q][bloc][24 + jl];
        }
        const float ig = sigm(g0), fg = sigm(g1), gg = tanhf(g2), og = sigm(g3);
        const size_t ci = (size_t)l * Bn * Hn + (size_t)(b0 + bloc) * Hn + (j0 + jl);
        float c = cst[ci];
        c = fg * c + ig * gg;
        cst[ci] = c;
        const float hv = og * tanhf(c);
        const unsigned short h1 = bf_hi(hv);
        const size_t ho = ((size_t)(l * 2 + wp) * Bn + (b0 + bloc)) * Hn + (j0 + jl);
        hh[ho] = h1;
        hl[ho] = bf_hi(hv - bf_f(h1));
        if (l == 2 && t == 1022)
          h3f[(size_t)(b0 + bloc) * Hn + (j0 + jl)] = hv;
      }
    }
  }
}

// FC epilogue: out2[b][o] = h3_final[b,:] . fc_w[o,:] + fc_b[o]
__global__ void fc_kernel(const float* __restrict__ h3f, const float* __restrict__ fcw,
                          const float* __restrict__ fcb, float* __restrict__ out) {
  const int gid = blockIdx.x * 256 + (int)threadIdx.x;
  if (gid >= Bn * INn) return;
  const int b = gid >> 8, o = gid & 255;
  const float* hr = h3f + (size_t)b * Hn;
  const float* wr = fcw + (size_t)o * Hn;
  float acc = fcb[o];
#pragma unroll 4
  for (int k = 0; k < Hn; k += 4) {
    const float4 hv = *reinterpret_cast<const float4*>(hr + k);
    const float4 wv = *reinterpret_cast<const float4*>(wr + k);
    acc = fmaf(hv.x, wv.x, acc); acc = fmaf(hv.y, wv.y, acc);
    acc = fmaf(hv.z, wv.z, acc); acc = fmaf(hv.w, wv.w, acc);
  }
  out[(size_t)Bn * Tn * INn + gid] = acc;
}

extern "C" void kernel_launch(void* const* d_in, const int* in_sizes, int n_in,
                              void* d_out, int out_size, void* d_ws, size_t ws_size,
                              hipStream_t stream) {
  const float* embed = (const float*)d_in[0];
  const float* wih1  = (const float*)d_in[1];
  const float* whh1  = (const float*)d_in[2];
  const float* bih1  = (const float*)d_in[3];
  const float* bhh1  = (const float*)d_in[4];
  const float* wih2  = (const float*)d_in[5];
  const float* whh2  = (const float*)d_in[6];
  const float* bih2  = (const float*)d_in[7];
  const float* bhh2  = (const float*)d_in[8];
  const float* wih3  = (const float*)d_in[9];
  const float* whh3  = (const float*)d_in[10];
  const float* bih3  = (const float*)d_in[11];
  const float* bhh3  = (const float*)d_in[12];
  const float* fcw   = (const float*)d_in[13];
  const float* fcb   = (const float*)d_in[14];
  float* outp = (float*)d_out;

  char* ws = (char*)d_ws;
  unsigned short* whi = (unsigned short*)(ws + WHI_OFF);
  unsigned short* wlo = (unsigned short*)(ws + WLO_OFF);
  float* bias         = (float*)(ws + BIAS_OFF);
  unsigned short* hh  = (unsigned short*)(ws + HH_OFF);
  unsigned short* hl  = (unsigned short*)(ws + HL_OFF);
  float* cst          = (float*)(ws + CST_OFF);
  float* h3f          = (float*)(ws + H3F_OFF);

  // Output 0: embed passthrough (128 MB d2d)
  hipMemcpyAsync(d_out, d_in[0], (size_t)Bn * Tn * INn * sizeof(float),
                 hipMemcpyDeviceToDevice, stream);

  pack_weights<<<2816, 256, 0, stream>>>(wih1, whh1, wih2, whh2, wih3, whh3, whi, wlo);
  pack_bias<<<24, 256, 0, stream>>>(bih1, bhh1, bih2, bhh2, bih3, bhh3, bias);
  init_state<<<512, 512, 0, stream>>>(hh, hl, cst);

  for (int p = 0; p <= 1024; ++p)
    lstm_phase<<<256, 1024, 0, stream>>>(p, embed, whi, wlo, bias, hh, hl, cst, h3f);

  fc_kernel<<<128, 256, 0, stream>>>(h3f, fcw, fcb, outp);
}